// Round 6
// baseline (395.446 us; speedup 1.0000x reference)
//
#include <hip/hip_runtime.h>
#include <hip/hip_bf16.h>

typedef __hip_bfloat16 bf16;
typedef unsigned short u16;
typedef __attribute__((ext_vector_type(8))) short bfrag;   // 8 bf16 = 4 VGPR
typedef __attribute__((ext_vector_type(4))) float cfrag;   // 4 f32 acc

union BF { bfrag v; u16 u[8]; unsigned w[4]; };
union CF { cfrag v; float f[4]; };

#define MFMA(a,b,c) __builtin_amdgcn_mfma_f32_16x16x32_bf16(a,b,c,0,0,0)

#define BB   256
#define NN   128
#define IND  9
#define HDD  128
#define NHH  8
#define LLY  4
#define OUTD 60
#define LOG2E 1.44269504f

__device__ __forceinline__ float b2f(bf16 v){ return __bfloat162float(v); }
__device__ __forceinline__ float u2f(u16 u){ return __uint_as_float(((unsigned)u) << 16); }
__device__ __forceinline__ u16 f2bf_bits(float f){
    unsigned u = __float_as_uint(f);
    return (u16)((u + 0x7FFFu + ((u >> 16) & 1u)) >> 16);   // RNE
}
__device__ __forceinline__ unsigned pk2(float a, float b){
    union { __hip_bfloat162 h; unsigned u; } c;
    c.h = __float22bfloat162_rn(make_float2(a, b));          // v_cvt_pk_bf16_f32
    return c.u;
}
__device__ __forceinline__ float wave_sum(float v){
    #pragma unroll
    for (int m = 32; m; m >>= 1) v += __shfl_xor(v, m, 64);
    return v;
}
__device__ __forceinline__ float ldin(const void* p, int i, bool isbf){
    return isbf ? b2f(((const bf16*)p)[i]) : ((const float*)p)[i];
}

struct SrcPtrs { const void* p[28]; };

__device__ const int CVT_OFF[28] = {
    0,294912,296064,296192,296320,296448,296576,296704,362240,362752,363264,363776,
    364288,495360,496384,627456,627968,628096,628224,644608,644736,652928,652992,656832,
    656896,673280,689664,706048};

// ====== fused prep: dtype-detect + convert + weight packs + ew2 + Aw ======
__global__ __launch_bounds__(256) void k_prep(
    SrcPtrs S, float* __restrict__ pf,
    u16* __restrict__ WT, u16* __restrict__ w1T, u16* __restrict__ w2T,
    u16* __restrict__ ew2, u16* __restrict__ Aw16, int* __restrict__ flagOut)
{
    const unsigned* xw = (const unsigned*)S.p[0];
    int lane = threadIdx.x & 63;
    int cnt = 0;
    for (int i = lane; i < 512; i += 64) {
        float v = __uint_as_float((xw[i] & 0xFFFFu) << 16);
        if (!(fabsf(v) < 32.f)) cnt++;
    }
    bool isbf = wave_sum((float)cnt) < 16.f;
    if (blockIdx.x == 0 && threadIdx.x == 0) *flagOut = isbf ? 1 : 0;

    int blk = blockIdx.x, tid = threadIdx.x;
    if (blk < 2822) {                              // fp32 conversion of all inputs
        int idx = blk * 256 + tid;                 // < 722432 exactly
        int y = 27;
        #pragma unroll 1
        for (int t = 1; t < 28; t++) if (idx < CVT_OFF[t]) { y = t - 1; break; }
        pf[idx] = ldin(S.p[y], idx - CVT_OFF[y], isbf);
    } else if (blk < 3078) {                       // WT[l][n128][k128] <- W[l][k][n]
        int j = (blk - 2822) * 256 + tid;
        int l = j >> 14, r = j & 16383, n = r >> 7, k = r & 127;
        WT[j] = f2bf_bits(ldin(S.p[7], (l << 14) + k * 128 + n, isbf));
    } else if (blk < 3590) {                       // w1T[l][n256][k128] <- fw1[l][k][n]
        int j = (blk - 3078) * 256 + tid;
        int l = j >> 15, r = j & 32767, n = r >> 7, k = r & 127;
        w1T[j] = f2bf_bits(ldin(S.p[12], (l << 15) + k * 256 + n, isbf));
    } else if (blk < 4102) {                       // w2T[l][n128][k256] <- fw2[l][k][n]
        int j = (blk - 3590) * 256 + tid;
        int l = j >> 15, r = j & 32767, n = r >> 8, k = r & 255;
        w2T[j] = f2bf_bits(ldin(S.p[14], (l << 15) + k * 128 + n, isbf));
    } else if (blk < 4166) {                       // ew2 = log2e * (mask ? ewa : -1e30)
        int j = (blk - 4102) * 256 + tid;
        float sav = ldin(S.p[24], j, isbf);
        float ewv = ldin(S.p[27], j, isbf);
        ew2[j] = f2bf_bits(sav > 0.f ? ewv * LOG2E : -1e30f);
    } else {                                       // Aw row-normalized, bf16
        __shared__ float red[2];
        int i = blk - 4166, j = tid & 127;
        float v = 0.f;
        if (tid < 128) {
            float wmv = ldin(S.p[25], i * 128 + j, isbf);
            float wpv = ldin(S.p[26], i * 128 + j, isbf);
            v = wmv / (1.f + __expf(-wpv));
            float sm = wave_sum(v);
            if ((tid & 63) == 0) red[tid >> 6] = sm;
        }
        __syncthreads();
        if (tid < 128) {
            float tot = red[0] + red[1];
            Aw16[i * 128 + j] = f2bf_bits(v / (tot + 1e-5f));
        }
    }
}

// ====== embedding: conv1d(k=1) + eval BN + relu ======
__global__ __launch_bounds__(256) void k_embed(
    const float* __restrict__ xf, const float* __restrict__ cw, const float* __restrict__ cb,
    const float* __restrict__ bg, const float* __restrict__ bbt,
    const float* __restrict__ bm, const float* __restrict__ bv,
    float* __restrict__ h, u16* __restrict__ h16)
{
    int b = blockIdx.x, half = blockIdx.y, tid = threadIdx.x;
    int d = tid & 127, nh = tid >> 7;
    float wreg[IND];
    #pragma unroll
    for (int k = 0; k < IND; k++) wreg[k] = cw[d * IND + k];
    float scale = rsqrtf(bv[d] + 1e-5f) * bg[d];
    float bias  = bbt[d] - bm[d] * scale;
    float cbd   = cb[d];
    #pragma unroll 1
    for (int it = 0; it < 32; it++) {
        int bn = b * NN + half * 64 + it * 2 + nh;  // wave-uniform
        float acc = cbd;
        #pragma unroll
        for (int k = 0; k < IND; k++) acc = fmaf(xf[bn * IND + k], wreg[k], acc);
        acc = fmaxf(fmaf(acc, scale, bias), 0.f);
        h[bn * HDD + d] = acc;
        h16[bn * HDD + d] = f2bf_bits(acc);
    }
}

// ====== per-layer megakernel: grid (256 graphs x 2 halves), 256 thr = 4 waves ======
// Code-size-disciplined: kk loops rolled; only register-indexed loops unrolled.
__global__ __launch_bounds__(256, 2) void k_layer(
    float* __restrict__ hg, u16* __restrict__ h16g,
    const u16* __restrict__ WT,
    const float* __restrict__ asrc, const float* __restrict__ adst,
    const u16* __restrict__ Aw16, const u16* __restrict__ ew2g,
    const float* __restrict__ lng, const float* __restrict__ lnb,
    const u16* __restrict__ w1T, const float* __restrict__ b1,
    const u16* __restrict__ w2T, const float* __restrict__ b2,
    const float* __restrict__ ng, const float* __restrict__ nb,
    float* __restrict__ pooled, int last)
{
    __shared__ __align__(16) u16 hpT[128 * 136];   // hp^T [dim][node] 34,816 B
    __shared__ __align__(16) u16 gbuf[64 * 136];   // g (local rows)   17,408 B
    __shared__ float st2[2048];                    // s2|t2 (log2e-scaled); psum alias
    __shared__ float lng_s[128], lnb_s[128], b2_s[128], ng_s[128], nb_s[128];
    __shared__ float b1_s[256];
    u16* hidb = hpT;                               // alias: hpT dead after phase 4
    float* s2 = st2;
    float* t2 = st2 + 1024;

    const int b = blockIdx.x, half = blockIdx.y;
    const int tid = threadIdx.x, lane = tid & 63, wv = tid >> 6;
    const int l15 = lane & 15, kg = lane >> 4;
    const int wrow = wv * 16;
    const int base = b * NN;

    if (tid < 128) {
        lng_s[tid] = lng[tid]; lnb_s[tid] = lnb[tid]; b2_s[tid] = b2[tid];
        if (last) { ng_s[tid] = ng[tid]; nb_s[tid] = nb[tid]; }
    }
    b1_s[tid] = b1[tid];

    // ---------- Phase 1: full hp = h @ W (M=128), 32 rows/wave ----------
    {
        CF acc[2][8];
        #pragma unroll
        for (int mt = 0; mt < 2; mt++)
            #pragma unroll
            for (int nt = 0; nt < 8; nt++)
                #pragma unroll
                for (int r = 0; r < 4; r++) acc[mt][nt].f[r] = 0.f;
        #pragma unroll 1
        for (int kk = 0; kk < 4; kk++) {
            bfrag af0 = *(const bfrag*)&h16g[(base + wv*32 +      l15) * 128 + kk*32 + kg*8];
            bfrag af1 = *(const bfrag*)&h16g[(base + wv*32 + 16 + l15) * 128 + kk*32 + kg*8];
            #pragma unroll
            for (int nt = 0; nt < 8; nt++) {
                bfrag bw = *(const bfrag*)&WT[(nt*16 + l15) * 128 + kk*32 + kg*8];
                acc[0][nt].v = MFMA(af0, bw, acc[0][nt].v);
                acc[1][nt].v = MFMA(af1, bw, acc[1][nt].v);
            }
        }
        #pragma unroll
        for (int mt = 0; mt < 2; mt++)
            #pragma unroll
            for (int nt = 0; nt < 8; nt++) {
                int col = nt*16 + l15;
                #pragma unroll
                for (int rp = 0; rp < 2; rp++) {
                    int row = wv*32 + mt*16 + kg*4 + rp*2;
                    *(unsigned*)&hpT[col * 136 + row] =
                        pk2(acc[mt][nt].f[rp*2], acc[mt][nt].f[rp*2+1]);
                }
            }
    }
    __syncthreads();

    // ---------- Phase 2: s,t head scores for ALL nodes, pre-scaled by log2e ----------
    {
        int node = tid & 127, which = tid >> 7;
        const float* av = which ? adst : asrc;
        float* dst = which ? t2 : s2;
        #pragma unroll 1
        for (int h = 0; h < 8; h++) {
            const u16* cp = &hpT[h * 16 * 136 + node];
            float a = 0.f;
            #pragma unroll
            for (int d = 0; d < 16; d++)
                a = fmaf(u2f(cp[d * 136]), av[h*16 + d], a);
            dst[h * 128 + node] = a * LOG2E;
        }
    }
    __syncthreads();

    // ---------- Phase 3: softmax (exp2 form, no max-sub) + strong MFMA ----------
    CF accS[8];
    #pragma unroll
    for (int nt = 0; nt < 8; nt++)
        #pragma unroll
        for (int r = 0; r < 4; r++) accS[nt].f[r] = 0.f;

    const int grow = half*64 + wrow + l15;         // A-frag row: global node i
    #pragma unroll 1
    for (int h = 0; h < 8; h++) {
        bfrag hb[4];
        #pragma unroll
        for (int kk = 0; kk < 4; kk++)
            hb[kk] = *(const bfrag*)&hpT[(h*16 + l15) * 136 + kk*32 + kg*8];
        float sA = s2[h * 128 + grow];
        float pv[4][8];
        float sm = 0.f;
        #pragma unroll
        for (int kk = 0; kk < 4; kk++) {
            const float* tp = &t2[h * 128 + kk*32 + kg*8];
            BF e2; e2.v = *(const bfrag*)&ew2g[grow * 128 + kk*32 + kg*8];
            #pragma unroll
            for (int j = 0; j < 8; j++) {
                float x2 = sA + tp[j];
                float lk = fmaxf(x2, 0.2f * x2);               // log2e*leaky(s+t)
                float p = __builtin_amdgcn_exp2f(lk + u2f(e2.u[j]));  // masked -> 0
                pv[kk][j] = p; sm += p;
            }
        }
        sm += __shfl_xor(sm, 16, 64);
        sm += __shfl_xor(sm, 32, 64);
        float inv = __builtin_amdgcn_rcpf(sm);
        #pragma unroll
        for (int kk = 0; kk < 4; kk++) {
            BF pb;
            #pragma unroll
            for (int q = 0; q < 4; q++)
                pb.w[q] = pk2(pv[kk][2*q] * inv, pv[kk][2*q+1] * inv);
            accS[h].v = MFMA(pb.v, hb[kk], accS[h].v);
        }
    }

    // ---------- Phase 4: weak = Aw @ hp ----------
    CF accW[8];
    #pragma unroll
    for (int nt = 0; nt < 8; nt++)
        #pragma unroll
        for (int r = 0; r < 4; r++) accW[nt].f[r] = 0.f;
    #pragma unroll 1
    for (int kk = 0; kk < 4; kk++) {
        bfrag awf = *(const bfrag*)&Aw16[grow * 128 + kk*32 + kg*8];
        #pragma unroll
        for (int nt = 0; nt < 8; nt++) {
            bfrag hb2 = *(const bfrag*)&hpT[(nt*16 + l15) * 136 + kk*32 + kg*8];
            accW[nt].v = MFMA(awf, hb2, accW[nt].v);
        }
    }

    // ---------- Phase 5: g = relu(0.6 s + 0.4 w), LN, write gbuf (local rows) ----------
    {
        float gv[8][4];
        #pragma unroll
        for (int nt = 0; nt < 8; nt++)
            #pragma unroll
            for (int r = 0; r < 4; r++)
                gv[nt][r] = fmaxf(0.6f * accS[nt].f[r] + 0.4f * accW[nt].f[r], 0.f);
        #pragma unroll
        for (int r = 0; r < 4; r++) {
            float s1 = 0.f, sq = 0.f;
            #pragma unroll
            for (int nt = 0; nt < 8; nt++) { float x = gv[nt][r]; s1 += x; sq = fmaf(x, x, sq); }
            #pragma unroll
            for (int m = 1; m <= 8; m <<= 1) { s1 += __shfl_xor(s1, m, 64); sq += __shfl_xor(sq, m, 64); }
            float mu = s1 * (1.f / 128.f);
            float var = sq * (1.f / 128.f) - mu * mu;
            float rs = rsqrtf(fmaxf(var, 0.f) + 1e-5f);
            int lrow = wrow + kg*4 + r;
            #pragma unroll
            for (int nt = 0; nt < 8; nt++) {
                int col = nt*16 + l15;
                gbuf[lrow * 136 + col] = f2bf_bits(fmaf((gv[nt][r] - mu) * rs, lng_s[col], lnb_s[col]));
            }
        }
    }
    __syncthreads();

    // ---------- Phase 6: FFN (M=64), two N-halves through LDS ----------
    CF acc2[8];
    #pragma unroll
    for (int nt = 0; nt < 8; nt++)
        #pragma unroll
        for (int r = 0; r < 4; r++) acc2[nt].f[r] = 0.f;

    #pragma unroll 1
    for (int nh = 0; nh < 2; nh++) {
        CF a1[8];
        #pragma unroll
        for (int nt = 0; nt < 8; nt++)
            #pragma unroll
            for (int r = 0; r < 4; r++) a1[nt].f[r] = 0.f;
        #pragma unroll 1
        for (int kk = 0; kk < 4; kk++) {
            bfrag gf = *(const bfrag*)&gbuf[(wrow + l15) * 136 + kk*32 + kg*8];
            #pragma unroll
            for (int nt = 0; nt < 8; nt++) {
                bfrag wf = *(const bfrag*)&w1T[(nh*128 + nt*16 + l15) * 128 + kk*32 + kg*8];
                a1[nt].v = MFMA(gf, wf, a1[nt].v);
            }
        }
        __syncthreads();                           // hidb region free (hpT readers done)
        #pragma unroll
        for (int nt = 0; nt < 8; nt++) {
            int col = nt*16 + l15;
            #pragma unroll
            for (int r = 0; r < 4; r++) {
                int lrow = wrow + kg*4 + r;
                hidb[lrow * 136 + col] = f2bf_bits(fmaxf(a1[nt].f[r] + b1_s[nh*128 + col], 0.f));
            }
        }
        __syncthreads();
        #pragma unroll 1
        for (int kk = 0; kk < 4; kk++) {
            bfrag hf = *(const bfrag*)&hidb[(wrow + l15) * 136 + kk*32 + kg*8];
            #pragma unroll
            for (int nt = 0; nt < 8; nt++) {
                bfrag wf = *(const bfrag*)&w2T[(nt*16 + l15) * 256 + nh*128 + kk*32 + kg*8];
                acc2[nt].v = MFMA(hf, wf, acc2[nt].v);
            }
        }
    }

    // ---------- Epilogue ----------
    float hv[8][4];
    #pragma unroll
    for (int nt = 0; nt < 8; nt++) {
        int col = nt*16 + l15;
        #pragma unroll
        for (int r = 0; r < 4; r++) {
            int gi = (base + half*64 + wrow + kg*4 + r) * HDD + col;
            hv[nt][r] = acc2[nt].f[r] + b2_s[col] + hg[gi];
        }
    }
    if (!last) {
        #pragma unroll
        for (int nt = 0; nt < 8; nt++) {
            int col = nt*16 + l15;
            #pragma unroll
            for (int r = 0; r < 4; r++) {
                int gi = (base + half*64 + wrow + kg*4 + r) * HDD + col;
                hg[gi] = hv[nt][r];
                h16g[gi] = f2bf_bits(hv[nt][r]);
            }
        }
    } else {
        // final LN per row + node-sum (proj commutes with mean) -> pooled
        float pacc[8];
        #pragma unroll
        for (int nt = 0; nt < 8; nt++) pacc[nt] = 0.f;
        #pragma unroll
        for (int r = 0; r < 4; r++) {
            float s1 = 0.f, sq = 0.f;
            #pragma unroll
            for (int nt = 0; nt < 8; nt++) { float x = hv[nt][r]; s1 += x; sq = fmaf(x, x, sq); }
            #pragma unroll
            for (int m = 1; m <= 8; m <<= 1) { s1 += __shfl_xor(s1, m, 64); sq += __shfl_xor(sq, m, 64); }
            float mu = s1 * (1.f / 128.f);
            float var = sq * (1.f / 128.f) - mu * mu;
            float rs = rsqrtf(fmaxf(var, 0.f) + 1e-5f);
            #pragma unroll
            for (int nt = 0; nt < 8; nt++) {
                int col = nt*16 + l15;
                pacc[nt] += fmaf((hv[nt][r] - mu) * rs, ng_s[col], nb_s[col]);
            }
        }
        __syncthreads();                           // st2 safe to reuse as psum
        float* psum = st2;                         // [16][128]
        #pragma unroll
        for (int nt = 0; nt < 8; nt++)
            psum[(wv*4 + kg) * 128 + nt*16 + l15] = pacc[nt];
        __syncthreads();
        if (tid < 128) {
            float tot = 0.f;
            #pragma unroll
            for (int i = 0; i < 16; i++) tot += psum[i * 128 + tid];
            atomicAdd(&pooled[b * HDD + tid], tot);
        }
    }
}

// ====== head: proj(mean) + MLP ======
__global__ __launch_bounds__(128) void k_head(
    const float* __restrict__ pooled, const float* __restrict__ pw, const float* __restrict__ pb,
    const float* __restrict__ hw1, const float* __restrict__ hb1,
    const float* __restrict__ hw2, const float* __restrict__ hb2,
    void* __restrict__ outv, const int* __restrict__ flag)
{
    int b = blockIdx.x, t = threadIdx.x;
    __shared__ float pm[128], pr[128], r1[64];
    pm[t] = pooled[b * HDD + t] * (1.f / 128.f);
    __syncthreads();
    float a = pb[t];
    #pragma unroll 4
    for (int k = 0; k < 128; k++) a = fmaf(pm[k], pw[k * 128 + t], a);
    pr[t] = a;
    __syncthreads();
    if (t < 64) {
        float a1 = hb1[t];
        #pragma unroll 4
        for (int k = 0; k < 128; k++) a1 = fmaf(pr[k], hw1[k * 64 + t], a1);
        r1[t] = fmaxf(a1, 0.f);
    }
    __syncthreads();
    if (t < OUTD) {
        float a2 = hb2[t];
        #pragma unroll 4
        for (int k = 0; k < 64; k++) a2 = fmaf(r1[k], hw2[k * OUTD + t], a2);
        if (*flag) ((bf16*)outv)[b * OUTD + t] = __float2bfloat16(a2);
        else       ((float*)outv)[b * OUTD + t] = a2;
    }
}

extern "C" void kernel_launch(void* const* d_in, const int* in_sizes, int n_in,
                              void* d_out, int out_size, void* d_ws, size_t ws_size,
                              hipStream_t stream)
{
    float* ws = (float*)d_ws;
    float* pf = ws;                                // converted fp32 params [0..722432)
    const float* xf   = pf + 0;
    const float* cw   = pf + 294912;
    const float* cb   = pf + 296064;
    const float* bg   = pf + 296192;
    const float* bbt  = pf + 296320;
    const float* bm   = pf + 296448;
    const float* bv   = pf + 296576;
    const float* asrcf= pf + 362240;
    const float* adstf= pf + 362752;
    const float* lng  = pf + 363264;
    const float* lnb  = pf + 363776;
    const float* fb1  = pf + 495360;
    const float* fb2  = pf + 627456;
    const float* ng   = pf + 627968;
    const float* nb   = pf + 628096;
    const float* pw   = pf + 628224;
    const float* pb   = pf + 644608;
    const float* hw1  = pf + 644736;
    const float* hb1  = pf + 652928;
    const float* hw2  = pf + 652992;
    const float* hb2  = pf + 656832;

    int*   flag   = (int*)(ws + 722432);
    float* h      = ws + 722448;                   // 4,194,304 f32
    float* pooled = h + 4194304;                   // 32,768 f32
    u16* h16    = (u16*)(pooled + 32768);          // 4,194,304 u16
    u16* WT16   = h16 + 4194304;                   // 65,536
    u16* w1T16  = WT16 + 65536;                    // 131,072
    u16* w2T16  = w1T16 + 131072;                  // 131,072
    u16* Aw16   = w2T16 + 131072;                  // 16,384
    u16* ew2p   = Aw16 + 16384;                    // 16,384

    SrcPtrs S;
    for (int i = 0; i < 28; i++) S.p[i] = d_in[i];

    k_prep<<<4294, 256, 0, stream>>>(S, pf, WT16, w1T16, w2T16, ew2p, Aw16, flag);
    hipMemsetAsync(pooled, 0, BB * HDD * sizeof(float), stream);
    k_embed<<<dim3(BB, 2), 256, 0, stream>>>(xf, cw, cb, bg, bbt, bm, bv, h, h16);

    for (int i = 0; i < LLY; i++) {
        k_layer<<<dim3(BB, 2), 256, 0, stream>>>(
            h, h16,
            WT16 + i * 16384, asrcf + i * 128, adstf + i * 128,
            Aw16, ew2p,
            lng + i * 128, lnb + i * 128,
            w1T16 + i * 32768, fb1 + i * 256,
            w2T16 + i * 32768, fb2 + i * 128,
            ng, nb, pooled, (i == LLY - 1) ? 1 : 0);
    }

    k_head<<<BB, 128, 0, stream>>>(pooled, pw, pb, hw1, hb1, hw2, hb2, d_out, flag);
}

// Round 7
// 393.686 us; speedup vs baseline: 1.0045x; 1.0045x over previous
//
#include <hip/hip_runtime.h>
#include <hip/hip_bf16.h>

typedef __hip_bfloat16 bf16;
typedef unsigned short u16;
typedef __attribute__((ext_vector_type(8))) short bfrag;   // 8 bf16 = 4 VGPR
typedef __attribute__((ext_vector_type(4))) float cfrag;   // 4 f32 acc

union BF { bfrag v; u16 u[8]; unsigned w[4]; };
union CF { cfrag v; float f[4]; };

#define MFMA(a,b,c) __builtin_amdgcn_mfma_f32_16x16x32_bf16(a,b,c,0,0,0)

#define BB   256
#define NN   128
#define IND  9
#define HDD  128
#define LLY  4
#define OUTD 60
#define LOG2E 1.44269504f

__device__ __forceinline__ float b2f(bf16 v){ return __bfloat162float(v); }
__device__ __forceinline__ float u2f(u16 u){ return __uint_as_float(((unsigned)u) << 16); }
__device__ __forceinline__ u16 f2bf_bits(float f){
    unsigned u = __float_as_uint(f);
    return (u16)((u + 0x7FFFu + ((u >> 16) & 1u)) >> 16);   // RNE
}
__device__ __forceinline__ unsigned pk2(float a, float b){
    union { __hip_bfloat162 h; unsigned u; } c;
    c.h = __float22bfloat162_rn(make_float2(a, b));          // v_cvt_pk_bf16_f32
    return c.u;
}
__device__ __forceinline__ float wave_sum(float v){
    #pragma unroll
    for (int m = 32; m; m >>= 1) v += __shfl_xor(v, m, 64);
    return v;
}
__device__ __forceinline__ float ldin(const void* p, int i, bool isbf){
    return isbf ? b2f(((const bf16*)p)[i]) : ((const float*)p)[i];
}

struct SrcPtrs { const void* p[28]; };

// compact f32 param buffer: only params actually consumed in f32
// cw0 cb1152 bg1280 bb1408 bm1536 bv1664 lng1792 lnb2304 fb1:2816 fb2:3840
// ng4352 nb4480 pw4608 pb20992 hw1:21120 hb1:29312 hw2:29376 hb2:33216 end33276
__device__ const int NCV_OFF[19] = {0,1152,1280,1408,1536,1664,1792,2304,2816,3840,
                                    4352,4480,4608,20992,21120,29312,29376,33216,33276};
__device__ const int NCV_SRC[18] = {1,2,3,4,5,6,10,11,13,15,16,17,18,19,20,21,22,23};

// ====== fused prep: detect + small-param convert + packs (WT,w1T,w2T,WAb,ew2,Aw) ======
// blocks: [0,131) cvt | [131,387) WT | [387,899) w1T | [899,1411) w2T
//         [1411,1443) WAb | [1443,1507) ew2 | [1507,1635) Aw
__global__ __launch_bounds__(256) void k_prep(
    SrcPtrs S, float* __restrict__ pf,
    u16* __restrict__ WT, u16* __restrict__ w1T, u16* __restrict__ w2T,
    u16* __restrict__ WAb, u16* __restrict__ ew2, u16* __restrict__ Aw16,
    int* __restrict__ flagOut)
{
    const unsigned* xw = (const unsigned*)S.p[0];
    int lane = threadIdx.x & 63;
    int cnt = 0;
    for (int i = lane; i < 512; i += 64) {
        float v = __uint_as_float((xw[i] & 0xFFFFu) << 16);
        if (!(fabsf(v) < 32.f)) cnt++;
    }
    bool isbf = wave_sum((float)cnt) < 16.f;
    if (blockIdx.x == 0 && threadIdx.x == 0) *flagOut = isbf ? 1 : 0;

    int blk = blockIdx.x, tid = threadIdx.x;
    if (blk < 131) {                               // small-param f32 convert
        int idx = blk * 256 + tid;
        if (idx < 33276) {
            int y = 17;
            #pragma unroll 1
            for (int t = 1; t < 18; t++) if (idx < NCV_OFF[t]) { y = t - 1; break; }
            pf[idx] = ldin(S.p[NCV_SRC[y]], idx - NCV_OFF[y], isbf);
        }
    } else if (blk < 387) {                        // WT[l][n128][k128] <- W[l][k][n]
        int j = (blk - 131) * 256 + tid;
        int l = j >> 14, r = j & 16383, n = r >> 7, k = r & 127;
        WT[j] = f2bf_bits(ldin(S.p[7], (l << 14) + k * 128 + n, isbf));
    } else if (blk < 899) {                        // w1T[l][n256][k128]
        int j = (blk - 387) * 256 + tid;
        int l = j >> 15, r = j & 32767, n = r >> 7, k = r & 127;
        w1T[j] = f2bf_bits(ldin(S.p[12], (l << 15) + k * 256 + n, isbf));
    } else if (blk < 1411) {                       // w2T[l][n128][k256]
        int j = (blk - 899) * 256 + tid;
        int l = j >> 15, r = j & 32767, n = r >> 8, k = r & 255;
        w2T[j] = f2bf_bits(ldin(S.p[14], (l << 15) + k * 128 + n, isbf));
    } else if (blk < 1443) {                       // WAb[l][n16][k128] = (W @ [asrc|adst])^T
        int j = (blk - 1411) * 256 + tid;          // 8192
        int l = j >> 11, r = j & 2047, n = r >> 7, k = r & 127;
        int h = n & 7;
        const void* ap = (n < 8) ? S.p[8] : S.p[9];
        float sacc = 0.f;
        #pragma unroll 1
        for (int d = 0; d < 16; d++)
            sacc += ldin(S.p[7], l * 16384 + k * 128 + h * 16 + d, isbf)
                  * ldin(ap, l * 128 + h * 16 + d, isbf);
        WAb[j] = f2bf_bits(sacc);
    } else if (blk < 1507) {                       // ew2 = log2e*(mask? ewa : -1e30)
        int j = (blk - 1443) * 256 + tid;
        float sav = ldin(S.p[24], j, isbf);
        float ewv = ldin(S.p[27], j, isbf);
        ew2[j] = f2bf_bits(sav > 0.f ? ewv * LOG2E : -1e30f);
    } else {                                       // Aw row-normalized, bf16
        __shared__ float red[2];
        int i = blk - 1507, j = tid & 127;
        float v = 0.f;
        if (tid < 128) {
            float wmv = ldin(S.p[25], i * 128 + j, isbf);
            float wpv = ldin(S.p[26], i * 128 + j, isbf);
            v = wmv / (1.f + __expf(-wpv));
            float sm = wave_sum(v);
            if ((tid & 63) == 0) red[tid >> 6] = sm;
        }
        __syncthreads();
        if (tid < 128) {
            float tot = red[0] + red[1];
            Aw16[i * 128 + j] = f2bf_bits(v / (tot + 1e-5f));
        }
    }
}

// ====== embedding (native-dtype x) + pooled zero ======
__global__ __launch_bounds__(256) void k_embed(
    const void* __restrict__ xraw, const int* __restrict__ flag,
    const float* __restrict__ pf,
    float* __restrict__ h, u16* __restrict__ h16, float* __restrict__ pooled)
{
    int b = blockIdx.x, half = blockIdx.y, tid = threadIdx.x;
    bool isbf = (*flag != 0);
    if (half == 0 && tid < 128) pooled[b * 128 + tid] = 0.f;
    int d = tid & 127, nh = tid >> 7;
    float wreg[IND];
    #pragma unroll
    for (int k = 0; k < IND; k++) wreg[k] = pf[d * IND + k];           // cw
    float scale = rsqrtf(pf[1664 + d] + 1e-5f) * pf[1280 + d];         // bv, bg
    float bias  = pf[1408 + d] - pf[1536 + d] * scale;                 // bb, bm
    float cbd   = pf[1152 + d];                                        // cb
    #pragma unroll 1
    for (int it = 0; it < 32; it++) {
        int bn = b * NN + half * 64 + it * 2 + nh;  // wave-uniform
        float acc = cbd;
        #pragma unroll
        for (int k = 0; k < IND; k++) acc = fmaf(ldin(xraw, bn * IND + k, isbf), wreg[k], acc);
        acc = fmaxf(fmaf(acc, scale, bias), 0.f);
        h[bn * HDD + d] = acc;
        h16[bn * HDD + d] = f2bf_bits(acc);
    }
}

// ====== per-layer megakernel: grid (256 graphs x 2 halves), 256 thr, 3 blocks/CU ======
__global__ __launch_bounds__(256, 3) void k_layer(
    float* __restrict__ hg, u16* __restrict__ h16g,
    const u16* __restrict__ WT, const u16* __restrict__ WAb,
    const u16* __restrict__ Aw16, const u16* __restrict__ ew2g,
    const float* __restrict__ lng, const float* __restrict__ lnb,
    const u16* __restrict__ w1T, const float* __restrict__ b1,
    const u16* __restrict__ w2T, const float* __restrict__ b2,
    const float* __restrict__ ng, const float* __restrict__ nb,
    float* __restrict__ pooled, int last)
{
    __shared__ __align__(16) u16 hpT[128 * 136];   // 34,816 B; P5+: gbuf=[0:17408), hidb=[17408:34816)
    __shared__ float st2[2048];                    // s2[8][128] | t2[8][128]; epilogue psum alias
    float* s2 = st2;
    float* t2 = st2 + 1024;
    u16* gbuf = hpT;
    u16* hidb = hpT + 64 * 136;

    const int b = blockIdx.x, half = blockIdx.y;
    const int tid = threadIdx.x, lane = tid & 63, wv = tid >> 6;
    const int l15 = lane & 15, kg = lane >> 4;
    const int wrow = wv * 16;
    const int base = b * NN;

    // per-thread bias/scale regs for owned cols nt*16+l15 (L2 loads, issued early)
    float lngr[8], lnbr[8], b2r[8];
    #pragma unroll
    for (int nt = 0; nt < 8; nt++) {
        int col = nt * 16 + l15;
        lngr[nt] = lng[col]; lnbr[nt] = lnb[col]; b2r[nt] = b2[col];
    }

    // ---------- Phase 1: hp = h @ W (M=128, 32 rows/wave) and s,t = h @ (W·a) ----------
    {
        CF acc[2][8], ast[2];
        #pragma unroll
        for (int mt = 0; mt < 2; mt++) {
            #pragma unroll
            for (int r = 0; r < 4; r++) ast[mt].f[r] = 0.f;
            #pragma unroll
            for (int nt = 0; nt < 8; nt++)
                #pragma unroll
                for (int r = 0; r < 4; r++) acc[mt][nt].f[r] = 0.f;
        }
        #pragma unroll 1
        for (int kk = 0; kk < 4; kk++) {
            bfrag af0 = *(const bfrag*)&h16g[(base + wv*32 +      l15) * 128 + kk*32 + kg*8];
            bfrag af1 = *(const bfrag*)&h16g[(base + wv*32 + 16 + l15) * 128 + kk*32 + kg*8];
            bfrag wab = *(const bfrag*)&WAb[l15 * 128 + kk*32 + kg*8];
            ast[0].v = MFMA(af0, wab, ast[0].v);
            ast[1].v = MFMA(af1, wab, ast[1].v);
            #pragma unroll
            for (int nt = 0; nt < 8; nt++) {
                bfrag bw = *(const bfrag*)&WT[(nt*16 + l15) * 128 + kk*32 + kg*8];
                acc[0][nt].v = MFMA(af0, bw, acc[0][nt].v);
                acc[1][nt].v = MFMA(af1, bw, acc[1][nt].v);
            }
        }
        #pragma unroll
        for (int mt = 0; mt < 2; mt++) {
            #pragma unroll
            for (int nt = 0; nt < 8; nt++) {
                int col = nt*16 + l15;
                #pragma unroll
                for (int rp = 0; rp < 2; rp++) {
                    int row = wv*32 + mt*16 + kg*4 + rp*2;
                    *(unsigned*)&hpT[col * 136 + row] =
                        pk2(acc[mt][nt].f[rp*2], acc[mt][nt].f[rp*2+1]);
                }
            }
            #pragma unroll
            for (int r = 0; r < 4; r++) {          // s,t from C-regs (col l15: 0-7=s, 8-15=t)
                int node = wv*32 + mt*16 + kg*4 + r;
                float v = ast[mt].f[r] * LOG2E;
                float* dst = (l15 < 8) ? &s2[l15 * 128 + node] : &t2[(l15 - 8) * 128 + node];
                *dst = v;
            }
        }
    }
    __syncthreads();

    // ---------- Phase 2 (was 4): weak = Aw @ hp ----------
    const int grow = half*64 + wrow + l15;         // A-frag row: global node i
    CF accW[8];
    #pragma unroll
    for (int nt = 0; nt < 8; nt++)
        #pragma unroll
        for (int r = 0; r < 4; r++) accW[nt].f[r] = 0.f;
    #pragma unroll 1
    for (int kk = 0; kk < 4; kk++) {
        bfrag awf = *(const bfrag*)&Aw16[grow * 128 + kk*32 + kg*8];
        #pragma unroll
        for (int nt = 0; nt < 8; nt++) {
            bfrag hb2 = *(const bfrag*)&hpT[(nt*16 + l15) * 136 + kk*32 + kg*8];
            accW[nt].v = MFMA(awf, hb2, accW[nt].v);
        }
    }

    // ---------- Phase 3: softmax (exp2, no max-sub) + strong MFMA ----------
    CF accS[8];
    #pragma unroll
    for (int nt = 0; nt < 8; nt++)
        #pragma unroll
        for (int r = 0; r < 4; r++) accS[nt].f[r] = 0.f;

    float ew2f[4][8];                              // h-invariant: hoist
    #pragma unroll
    for (int kk = 0; kk < 4; kk++) {
        BF e2; e2.v = *(const bfrag*)&ew2g[grow * 128 + kk*32 + kg*8];
        #pragma unroll
        for (int j = 0; j < 8; j++) ew2f[kk][j] = u2f(e2.u[j]);
    }
    #pragma unroll 1
    for (int h = 0; h < 8; h++) {
        bfrag hb[4];
        #pragma unroll
        for (int kk = 0; kk < 4; kk++)
            hb[kk] = *(const bfrag*)&hpT[(h*16 + l15) * 136 + kk*32 + kg*8];
        float sA = s2[h * 128 + grow];
        float pv[4][8];
        float sm = 0.f;
        #pragma unroll
        for (int kk = 0; kk < 4; kk++) {
            const float* tp = &t2[h * 128 + kk*32 + kg*8];
            #pragma unroll
            for (int j = 0; j < 8; j++) {
                float x2 = sA + tp[j];
                float lk = fmaxf(x2, 0.2f * x2);               // log2e*leaky(s+t)
                float p = __builtin_amdgcn_exp2f(lk + ew2f[kk][j]);  // masked -> 0
                pv[kk][j] = p; sm += p;
            }
        }
        sm += __shfl_xor(sm, 16, 64);
        sm += __shfl_xor(sm, 32, 64);
        float inv = __builtin_amdgcn_rcpf(sm);
        #pragma unroll
        for (int kk = 0; kk < 4; kk++) {
            BF pb;
            #pragma unroll
            for (int q = 0; q < 4; q++)
                pb.w[q] = pk2(pv[kk][2*q] * inv, pv[kk][2*q+1] * inv);
            accS[h].v = MFMA(pb.v, hb[kk], accS[h].v);
        }
    }

    // ---------- Phase 4: g = relu(0.6 s + 0.4 w) + LN (regs) ----------
    float gv[8][4];
    #pragma unroll
    for (int nt = 0; nt < 8; nt++)
        #pragma unroll
        for (int r = 0; r < 4; r++)
            gv[nt][r] = fmaxf(0.6f * accS[nt].f[r] + 0.4f * accW[nt].f[r], 0.f);
    u16 gb16[8][4];
    #pragma unroll
    for (int r = 0; r < 4; r++) {
        float s1 = 0.f, sq = 0.f;
        #pragma unroll
        for (int nt = 0; nt < 8; nt++) { float x = gv[nt][r]; s1 += x; sq = fmaf(x, x, sq); }
        #pragma unroll
        for (int m = 1; m <= 8; m <<= 1) { s1 += __shfl_xor(s1, m, 64); sq += __shfl_xor(sq, m, 64); }
        float mu = s1 * (1.f / 128.f);
        float var = sq * (1.f / 128.f) - mu * mu;
        float rs = rsqrtf(fmaxf(var, 0.f) + 1e-5f);
        #pragma unroll
        for (int nt = 0; nt < 8; nt++)
            gb16[nt][r] = f2bf_bits(fmaf((gv[nt][r] - mu) * rs, lngr[nt], lnbr[nt]));
    }
    __syncthreads();                               // all waves done reading hpT
    #pragma unroll
    for (int nt = 0; nt < 8; nt++) {
        int col = nt*16 + l15;
        #pragma unroll
        for (int r = 0; r < 4; r++)
            gbuf[(wrow + kg*4 + r) * 136 + col] = gb16[nt][r];
    }
    __syncthreads();

    // ---------- Phase 5: FFN (M=64), two N-halves through LDS ----------
    CF acc2[8];
    #pragma unroll
    for (int nt = 0; nt < 8; nt++)
        #pragma unroll
        for (int r = 0; r < 4; r++) acc2[nt].f[r] = 0.f;

    #pragma unroll 1
    for (int nh = 0; nh < 2; nh++) {
        float b1r[8];
        #pragma unroll
        for (int nt = 0; nt < 8; nt++) b1r[nt] = b1[nh*128 + nt*16 + l15];
        CF a1[8];
        #pragma unroll
        for (int nt = 0; nt < 8; nt++)
            #pragma unroll
            for (int r = 0; r < 4; r++) a1[nt].f[r] = 0.f;
        #pragma unroll 1
        for (int kk = 0; kk < 4; kk++) {
            bfrag gf = *(const bfrag*)&gbuf[(wrow + l15) * 136 + kk*32 + kg*8];
            #pragma unroll
            for (int nt = 0; nt < 8; nt++) {
                bfrag wf = *(const bfrag*)&w1T[(nh*128 + nt*16 + l15) * 128 + kk*32 + kg*8];
                a1[nt].v = MFMA(gf, wf, a1[nt].v);
            }
        }
        __syncthreads();                           // prior hidb readers done
        #pragma unroll
        for (int nt = 0; nt < 8; nt++) {
            int col = nt*16 + l15;
            #pragma unroll
            for (int r = 0; r < 4; r++)
                hidb[(wrow + kg*4 + r) * 136 + col] = f2bf_bits(fmaxf(a1[nt].f[r] + b1r[nt], 0.f));
        }
        __syncthreads();
        #pragma unroll 1
        for (int kk = 0; kk < 4; kk++) {
            bfrag hf = *(const bfrag*)&hidb[(wrow + l15) * 136 + kk*32 + kg*8];
            #pragma unroll
            for (int nt = 0; nt < 8; nt++) {
                bfrag wf = *(const bfrag*)&w2T[(nt*16 + l15) * 256 + nh*128 + kk*32 + kg*8];
                acc2[nt].v = MFMA(hf, wf, acc2[nt].v);
            }
        }
    }

    // ---------- Epilogue ----------
    float hv[8][4];
    #pragma unroll
    for (int nt = 0; nt < 8; nt++) {
        #pragma unroll
        for (int r = 0; r < 4; r++) {
            int gi = (base + half*64 + wrow + kg*4 + r) * HDD + nt*16 + l15;
            hv[nt][r] = acc2[nt].f[r] + b2r[nt] + hg[gi];
        }
    }
    if (!last) {
        #pragma unroll
        for (int nt = 0; nt < 8; nt++) {
            #pragma unroll
            for (int r = 0; r < 4; r++) {
                int gi = (base + half*64 + wrow + kg*4 + r) * HDD + nt*16 + l15;
                hg[gi] = hv[nt][r];
                h16g[gi] = f2bf_bits(hv[nt][r]);
            }
        }
    } else {
        // final LN per row + node-sum (proj commutes with mean) -> pooled
        float ngr[8], nbr[8];
        #pragma unroll
        for (int nt = 0; nt < 8; nt++) { int col = nt*16 + l15; ngr[nt] = ng[col]; nbr[nt] = nb[col]; }
        float pacc[8];
        #pragma unroll
        for (int nt = 0; nt < 8; nt++) pacc[nt] = 0.f;
        #pragma unroll
        for (int r = 0; r < 4; r++) {
            float s1 = 0.f, sq = 0.f;
            #pragma unroll
            for (int nt = 0; nt < 8; nt++) { float x = hv[nt][r]; s1 += x; sq = fmaf(x, x, sq); }
            #pragma unroll
            for (int m = 1; m <= 8; m <<= 1) { s1 += __shfl_xor(s1, m, 64); sq += __shfl_xor(sq, m, 64); }
            float mu = s1 * (1.f / 128.f);
            float var = sq * (1.f / 128.f) - mu * mu;
            float rs = rsqrtf(fmaxf(var, 0.f) + 1e-5f);
            #pragma unroll
            for (int nt = 0; nt < 8; nt++)
                pacc[nt] += fmaf((hv[nt][r] - mu) * rs, ngr[nt], nbr[nt]);
        }
        __syncthreads();                           // st2 free -> psum
        float* psum = st2;                         // [16][128]
        #pragma unroll
        for (int nt = 0; nt < 8; nt++)
            psum[(wv*4 + kg) * 128 + nt*16 + l15] = pacc[nt];
        __syncthreads();
        if (tid < 128) {
            float tot = 0.f;
            #pragma unroll
            for (int i = 0; i < 16; i++) tot += psum[i * 128 + tid];
            atomicAdd(&pooled[b * HDD + tid], tot);
        }
    }
}

// ====== head: proj(mean) + MLP ======
__global__ __launch_bounds__(128) void k_head(
    const float* __restrict__ pooled, const float* __restrict__ pf,
    void* __restrict__ outv, const int* __restrict__ flag)
{
    const float* pw  = pf + 4608;
    const float* pb  = pf + 20992;
    const float* hw1 = pf + 21120;
    const float* hb1 = pf + 29312;
    const float* hw2 = pf + 29376;
    const float* hb2 = pf + 33216;
    int b = blockIdx.x, t = threadIdx.x;
    __shared__ float pm[128], pr[128], r1[64];
    pm[t] = pooled[b * HDD + t] * (1.f / 128.f);
    __syncthreads();
    float a = pb[t];
    #pragma unroll 4
    for (int k = 0; k < 128; k++) a = fmaf(pm[k], pw[k * 128 + t], a);
    pr[t] = a;
    __syncthreads();
    if (t < 64) {
        float a1 = hb1[t];
        #pragma unroll 4
        for (int k = 0; k < 128; k++) a1 = fmaf(pr[k], hw1[k * 64 + t], a1);
        r1[t] = fmaxf(a1, 0.f);
    }
    __syncthreads();
    if (t < OUTD) {
        float a2 = hb2[t];
        #pragma unroll 4
        for (int k = 0; k < 64; k++) a2 = fmaf(r1[k], hw2[k * OUTD + t], a2);
        if (*flag) ((bf16*)outv)[b * OUTD + t] = __float2bfloat16(a2);
        else       ((float*)outv)[b * OUTD + t] = a2;
    }
}

extern "C" void kernel_launch(void* const* d_in, const int* in_sizes, int n_in,
                              void* d_out, int out_size, void* d_ws, size_t ws_size,
                              hipStream_t stream)
{
    float* ws = (float*)d_ws;
    float* pf = ws;                                // compact f32 params [0..33276)
    const float* lng  = pf + 1792;
    const float* lnb  = pf + 2304;
    const float* fb1  = pf + 2816;
    const float* fb2  = pf + 3840;
    const float* ng   = pf + 4352;
    const float* nb   = pf + 4480;

    int*   flag   = (int*)(ws + 33280);
    float* h      = ws + 33536;                    // 4,194,304 f32
    float* pooled = h + 4194304;                   // 32,768 f32
    u16* h16    = (u16*)(pooled + 32768);          // 4,194,304 u16
    u16* WT16   = h16 + 4194304;                   // 65,536
    u16* w1T16  = WT16 + 65536;                    // 131,072
    u16* w2T16  = w1T16 + 131072;                  // 131,072
    u16* WAb16  = w2T16 + 131072;                  // 8,192
    u16* Aw16   = WAb16 + 8192;                    // 16,384
    u16* ew2p   = Aw16 + 16384;                    // 16,384

    SrcPtrs S;
    for (int i = 0; i < 28; i++) S.p[i] = d_in[i];

    k_prep<<<1635, 256, 0, stream>>>(S, pf, WT16, w1T16, w2T16, WAb16, ew2p, Aw16, flag);
    k_embed<<<dim3(BB, 2), 256, 0, stream>>>(d_in[0], flag, pf, h, h16, pooled);

    for (int i = 0; i < LLY; i++) {
        k_layer<<<dim3(BB, 2), 256, 0, stream>>>(
            h, h16,
            WT16 + i * 16384, WAb16 + i * 2048,
            Aw16, ew2p,
            lng + i * 128, lnb + i * 128,
            w1T16 + i * 32768, fb1 + i * 256,
            w2T16 + i * 32768, fb2 + i * 128,
            ng, nb, pooled, (i == LLY - 1) ? 1 : 0);
    }

    k_head<<<BB, 128, 0, stream>>>(pooled, pf, d_out, flag);
}

// Round 8
// 352.911 us; speedup vs baseline: 1.1205x; 1.1155x over previous
//
#include <hip/hip_runtime.h>
#include <hip/hip_bf16.h>

typedef __hip_bfloat16 bf16;
typedef unsigned short u16;
typedef __attribute__((ext_vector_type(8))) short bfrag;   // 8 bf16 = 4 VGPR
typedef __attribute__((ext_vector_type(4))) float cfrag;   // 4 f32 acc

union BF { bfrag v; u16 u[8]; unsigned w[4]; };
union CF { cfrag v; float f[4]; };

#define MFMA(a,b,c) __builtin_amdgcn_mfma_f32_16x16x32_bf16(a,b,c,0,0,0)

#define BB   256
#define NN   128
#define IND  9
#define HDD  128
#define LLY  4
#define OUTD 60
#define LOG2E 1.44269504f
#define STR  136                                  // LDS row stride (u16), 16B-multiple

__device__ __forceinline__ float b2f(bf16 v){ return __bfloat162float(v); }
__device__ __forceinline__ float u2f(u16 u){ return __uint_as_float(((unsigned)u) << 16); }
__device__ __forceinline__ u16 f2bf_bits(float f){
    unsigned u = __float_as_uint(f);
    return (u16)((u + 0x7FFFu + ((u >> 16) & 1u)) >> 16);   // RNE
}
__device__ __forceinline__ unsigned pk2(float a, float b){
    union { __hip_bfloat162 h; unsigned u; } c;
    c.h = __float22bfloat162_rn(make_float2(a, b));          // v_cvt_pk_bf16_f32
    return c.u;
}
__device__ __forceinline__ float wave_sum(float v){
    #pragma unroll
    for (int m = 32; m; m >>= 1) v += __shfl_xor(v, m, 64);
    return v;
}
__device__ __forceinline__ float ldin(const void* p, int i, bool isbf){
    return isbf ? b2f(((const bf16*)p)[i]) : ((const float*)p)[i];
}

struct SrcPtrs { const void* p[28]; };

// compact f32 param buffer layout (element offsets):
// cw0 cb1152 bg1280 bb1408 bm1536 bv1664 lng1792 lnb2304 fb1:2816 fb2:3840
// ng4352 nb4480 pw4608 pb20992 hw1:21120 hb1:29312 hw2:29376 hb2:33216 end33276
__device__ const int NCV_OFF[19] = {0,1152,1280,1408,1536,1664,1792,2304,2816,3840,
                                    4352,4480,4608,20992,21120,29312,29376,33216,33276};
__device__ const int NCV_SRC[18] = {1,2,3,4,5,6,10,11,13,15,16,17,18,19,20,21,22,23};

// ====== fused prep: detect + small-param convert + packs (WT,w1T,w2T,WAb,ew2,Aw) ======
__global__ __launch_bounds__(256) void k_prep(
    SrcPtrs S, float* __restrict__ pf,
    u16* __restrict__ WT, u16* __restrict__ w1T, u16* __restrict__ w2T,
    u16* __restrict__ WAb, u16* __restrict__ ew2, u16* __restrict__ Aw16,
    int* __restrict__ flagOut)
{
    const unsigned* xw = (const unsigned*)S.p[0];
    int lane = threadIdx.x & 63;
    int cnt = 0;
    for (int i = lane; i < 512; i += 64) {
        float v = __uint_as_float((xw[i] & 0xFFFFu) << 16);
        if (!(fabsf(v) < 32.f)) cnt++;
    }
    bool isbf = wave_sum((float)cnt) < 16.f;
    if (blockIdx.x == 0 && threadIdx.x == 0) *flagOut = isbf ? 1 : 0;

    int blk = blockIdx.x, tid = threadIdx.x;
    if (blk < 131) {                               // small-param f32 convert
        int idx = blk * 256 + tid;
        if (idx < 33276) {
            int y = 17;
            #pragma unroll 1
            for (int t = 1; t < 18; t++) if (idx < NCV_OFF[t]) { y = t - 1; break; }
            pf[idx] = ldin(S.p[NCV_SRC[y]], idx - NCV_OFF[y], isbf);
        }
    } else if (blk < 387) {                        // WT[l][n128][k128] <- W[l][k][n]
        int j = (blk - 131) * 256 + tid;
        int l = j >> 14, r = j & 16383, n = r >> 7, k = r & 127;
        WT[j] = f2bf_bits(ldin(S.p[7], (l << 14) + k * 128 + n, isbf));
    } else if (blk < 899) {                        // w1T[l][n256][k128]
        int j = (blk - 387) * 256 + tid;
        int l = j >> 15, r = j & 32767, n = r >> 7, k = r & 127;
        w1T[j] = f2bf_bits(ldin(S.p[12], (l << 15) + k * 256 + n, isbf));
    } else if (blk < 1411) {                       // w2T[l][n128][k256]
        int j = (blk - 899) * 256 + tid;
        int l = j >> 15, r = j & 32767, n = r >> 8, k = r & 255;
        w2T[j] = f2bf_bits(ldin(S.p[14], (l << 15) + k * 128 + n, isbf));
    } else if (blk < 1443) {                       // WAb[l][n16][k128] = (W @ [asrc|adst])^T
        int j = (blk - 1411) * 256 + tid;          // 8192
        int l = j >> 11, r = j & 2047, n = r >> 7, k = r & 127;
        int h = n & 7;
        const void* ap = (n < 8) ? S.p[8] : S.p[9];
        float sacc = 0.f;
        #pragma unroll 1
        for (int d = 0; d < 16; d++)
            sacc += ldin(S.p[7], l * 16384 + k * 128 + h * 16 + d, isbf)
                  * ldin(ap, l * 128 + h * 16 + d, isbf);
        WAb[j] = f2bf_bits(sacc);
    } else if (blk < 1507) {                       // ew2 = log2e*(mask? ewa : -1e30)
        int j = (blk - 1443) * 256 + tid;
        float sav = ldin(S.p[24], j, isbf);
        float ewv = ldin(S.p[27], j, isbf);
        ew2[j] = f2bf_bits(sav > 0.f ? ewv * LOG2E : -1e30f);
    } else {                                       // Aw row-normalized, bf16
        __shared__ float red[2];
        int i = blk - 1507, j = tid & 127;
        float v = 0.f;
        if (tid < 128) {
            float wmv = ldin(S.p[25], i * 128 + j, isbf);
            float wpv = ldin(S.p[26], i * 128 + j, isbf);
            v = wmv / (1.f + __expf(-wpv));
            float sm = wave_sum(v);
            if ((tid & 63) == 0) red[tid >> 6] = sm;
        }
        __syncthreads();
        if (tid < 128) {
            float tot = red[0] + red[1];
            Aw16[i * 128 + j] = f2bf_bits(v / (tot + 1e-5f));
        }
    }
}

// ====== whole-network megakernel: 1 block per graph, 512 thr = 8 waves, 16 rows/wave ======
// LDS: Abuf = h16A / hid (wave-private rows), Bbuf = hpT / gbuf (hpT cross-wave),
// st2 = s2 f32 [8][128] | t2 bf16 [8][128] | head scratch. 77,824 B total.
#define LDSB (2*128*STR*2 + 8192)
__global__ __launch_bounds__(512, 2) void k_net(
    const void* __restrict__ xraw, const int* __restrict__ flag,
    const float* __restrict__ pf,
    const u16* __restrict__ WTg, const u16* __restrict__ WAbg,
    const u16* __restrict__ Awg, const u16* __restrict__ ew2g,
    const u16* __restrict__ w1Tg, const u16* __restrict__ w2Tg,
    void* __restrict__ outv)
{
    extern __shared__ __align__(16) char smem[];
    u16* Abuf = (u16*)smem;                    // [128][STR] h16A, later hid (per-wave rows)
    u16* Bbuf = Abuf + 128 * STR;              // [128][STR] hpT (cross-wave), later gbuf
    float* st2 = (float*)(Bbuf + 128 * STR);   // 2048 f32
    float* s2  = st2;                          // [8][128] f32
    u16*   t2u = (u16*)(st2 + 1024);           // [8][128] bf16

    const int b = blockIdx.x;
    const int tid = threadIdx.x, lane = tid & 63, wv = tid >> 6;
    const int l15 = lane & 15, kg = lane >> 4;
    const int wrow = wv * 16;
    const bool isbf = (*flag != 0);

    float hreg[8][4];                          // residual h, C-frag layout (own 16 rows)

    // ---------- embed: conv1d + BN + relu, into hreg + Abuf ----------
    {
        float xr[4][9];
        #pragma unroll
        for (int r = 0; r < 4; r++) {
            int bn = b * NN + wrow + kg * 4 + r;
            #pragma unroll
            for (int k = 0; k < IND; k++) xr[r][k] = ldin(xraw, bn * IND + k, isbf);
        }
        #pragma unroll 1
        for (int nt = 0; nt < 8; nt++) {
            int d = nt * 16 + l15;
            float cwreg[IND];
            #pragma unroll
            for (int k = 0; k < IND; k++) cwreg[k] = pf[d * IND + k];
            float scale = rsqrtf(pf[1664 + d] + 1e-5f) * pf[1280 + d];
            float bias  = pf[1408 + d] - pf[1536 + d] * scale;
            float cbd   = pf[1152 + d];
            #pragma unroll
            for (int r = 0; r < 4; r++) {
                float a = cbd;
                #pragma unroll
                for (int k = 0; k < IND; k++) a = fmaf(xr[r][k], cwreg[k], a);
                a = fmaxf(fmaf(a, scale, bias), 0.f);
                hreg[nt][r] = a;
                Abuf[(wrow + kg * 4 + r) * STR + d] = f2bf_bits(a);
            }
        }
    }

    const int arow = wrow + l15;               // this lane's A-frag row

    // ---------- 4 layers ----------
    #pragma unroll 1
    for (int l = 0; l < LLY; l++) {
        const u16* WT  = WTg  + l * 16384;
        const u16* WAb = WAbg + l * 2048;
        const u16* w1T = w1Tg + l * 32768;
        const u16* w2T = w2Tg + l * 32768;
        const float* fb1 = pf + 2816 + l * 256;
        const float* fb2 = pf + 3840 + l * 128;
        const float* lng = pf + 1792 + l * 128;
        const float* lnb = pf + 2304 + l * 128;

        __syncthreads();                       // Bbuf free: prior-layer gbuf readers done

        // P1: hp = h @ W (own 16 rows) + s,t = h @ (W·a)
        {
            CF acc[8], ast;
            #pragma unroll
            for (int r = 0; r < 4; r++) ast.f[r] = 0.f;
            #pragma unroll
            for (int nt = 0; nt < 8; nt++)
                #pragma unroll
                for (int r = 0; r < 4; r++) acc[nt].f[r] = 0.f;
            #pragma unroll 1
            for (int kk = 0; kk < 4; kk++) {
                bfrag af  = *(const bfrag*)&Abuf[arow * STR + kk*32 + kg*8];
                bfrag wab = *(const bfrag*)&WAb[l15 * 128 + kk*32 + kg*8];
                ast.v = MFMA(af, wab, ast.v);
                #pragma unroll
                for (int nt = 0; nt < 8; nt++) {
                    bfrag bw = *(const bfrag*)&WT[(nt*16 + l15) * 128 + kk*32 + kg*8];
                    acc[nt].v = MFMA(af, bw, acc[nt].v);
                }
            }
            #pragma unroll
            for (int nt = 0; nt < 8; nt++) {
                int col = nt*16 + l15;
                #pragma unroll
                for (int rp = 0; rp < 2; rp++) {
                    int row = wrow + kg*4 + rp*2;
                    *(unsigned*)&Bbuf[col * STR + row] = pk2(acc[nt].f[rp*2], acc[nt].f[rp*2+1]);
                }
            }
            #pragma unroll
            for (int r = 0; r < 4; r++) {      // s (cols 0-7) f32, t (cols 8-15) bf16
                int node = wrow + kg*4 + r;
                float v = ast.f[r] * LOG2E;
                if (l15 < 8) s2[l15 * 128 + node] = v;
                else         t2u[(l15 - 8) * 128 + node] = f2bf_bits(v);
            }
        }
        __syncthreads();                       // hpT, s2, t2 ready

        // P2: weak = Aw @ hp
        CF accW[8];
        #pragma unroll
        for (int nt = 0; nt < 8; nt++)
            #pragma unroll
            for (int r = 0; r < 4; r++) accW[nt].f[r] = 0.f;
        #pragma unroll 1
        for (int kk = 0; kk < 4; kk++) {
            bfrag awf = *(const bfrag*)&Awg[arow * 128 + kk*32 + kg*8];
            #pragma unroll
            for (int nt = 0; nt < 8; nt++) {
                bfrag hb2 = *(const bfrag*)&Bbuf[(nt*16 + l15) * STR + kk*32 + kg*8];
                accW[nt].v = MFMA(awf, hb2, accW[nt].v);
            }
        }

        // P3: softmax (exp2, no max-sub) + strong MFMA
        CF accS[8];
        #pragma unroll
        for (int nt = 0; nt < 8; nt++)
            #pragma unroll
            for (int r = 0; r < 4; r++) accS[nt].f[r] = 0.f;
        #pragma unroll 1
        for (int h = 0; h < 8; h++) {
            bfrag hb[4];
            #pragma unroll
            for (int kk = 0; kk < 4; kk++)
                hb[kk] = *(const bfrag*)&Bbuf[(h*16 + l15) * STR + kk*32 + kg*8];
            float sA = s2[h * 128 + arow];
            float pv[4][8];
            float sm = 0.f;
            #pragma unroll
            for (int kk = 0; kk < 4; kk++) {
                BF tb; tb.v = *(const bfrag*)&t2u[h * 128 + kk*32 + kg*8];
                BF e2; e2.v = *(const bfrag*)&ew2g[arow * 128 + kk*32 + kg*8];
                #pragma unroll
                for (int j = 0; j < 8; j++) {
                    float x2 = sA + u2f(tb.u[j]);
                    float lk = fmaxf(x2, 0.2f * x2);                 // log2e*leaky(s+t)
                    float p = __builtin_amdgcn_exp2f(lk + u2f(e2.u[j]));  // masked -> 0
                    pv[kk][j] = p; sm += p;
                }
            }
            sm += __shfl_xor(sm, 16, 64);
            sm += __shfl_xor(sm, 32, 64);
            float inv = __builtin_amdgcn_rcpf(sm);
            #pragma unroll
            for (int kk = 0; kk < 4; kk++) {
                BF pb;
                #pragma unroll
                for (int q = 0; q < 4; q++)
                    pb.w[q] = pk2(pv[kk][2*q] * inv, pv[kk][2*q+1] * inv);
                accS[h].v = MFMA(pb.v, hb[kk], accS[h].v);
            }
        }
        __syncthreads();                       // all hpT reads done -> Bbuf reusable as gbuf

        // P4: g = relu(0.6 s + 0.4 w) + LN -> gbuf (own rows; no barrier needed after)
        {
            float gv[8][4];
            #pragma unroll
            for (int nt = 0; nt < 8; nt++)
                #pragma unroll
                for (int r = 0; r < 4; r++)
                    gv[nt][r] = fmaxf(0.6f * accS[nt].f[r] + 0.4f * accW[nt].f[r], 0.f);
            #pragma unroll
            for (int r = 0; r < 4; r++) {
                float s1 = 0.f, sq = 0.f;
                #pragma unroll
                for (int nt = 0; nt < 8; nt++) { float x = gv[nt][r]; s1 += x; sq = fmaf(x, x, sq); }
                #pragma unroll
                for (int m = 1; m <= 8; m <<= 1) { s1 += __shfl_xor(s1, m, 64); sq += __shfl_xor(sq, m, 64); }
                float mu = s1 * (1.f / 128.f);
                float var = sq * (1.f / 128.f) - mu * mu;
                float rs = rsqrtf(fmaxf(var, 0.f) + 1e-5f);
                #pragma unroll
                for (int nt = 0; nt < 8; nt++) {
                    int col = nt*16 + l15;
                    Bbuf[(wrow + kg*4 + r) * STR + col] =
                        f2bf_bits(fmaf((gv[nt][r] - mu) * rs, lng[col], lnb[col]));
                }
            }
        }

        // P5: FFN, two N-halves; gbuf/hid are wave-private rows -> no barriers
        CF acc2[8];
        #pragma unroll
        for (int nt = 0; nt < 8; nt++)
            #pragma unroll
            for (int r = 0; r < 4; r++) acc2[nt].f[r] = 0.f;
        #pragma unroll 1
        for (int nh = 0; nh < 2; nh++) {
            CF a1[8];
            #pragma unroll
            for (int nt = 0; nt < 8; nt++)
                #pragma unroll
                for (int r = 0; r < 4; r++) a1[nt].f[r] = 0.f;
            #pragma unroll 1
            for (int kk = 0; kk < 4; kk++) {
                bfrag gf = *(const bfrag*)&Bbuf[arow * STR + kk*32 + kg*8];
                #pragma unroll
                for (int nt = 0; nt < 8; nt++) {
                    bfrag wf = *(const bfrag*)&w1T[(nh*128 + nt*16 + l15) * 128 + kk*32 + kg*8];
                    a1[nt].v = MFMA(gf, wf, a1[nt].v);
                }
            }
            #pragma unroll
            for (int nt = 0; nt < 8; nt++) {
                int col = nt*16 + l15;
                float b1v = fb1[nh*128 + col];
                #pragma unroll
                for (int r = 0; r < 4; r++)
                    Abuf[(wrow + kg*4 + r) * STR + col] = f2bf_bits(fmaxf(a1[nt].f[r] + b1v, 0.f));
            }
            #pragma unroll 1
            for (int kk = 0; kk < 4; kk++) {
                bfrag hf = *(const bfrag*)&Abuf[arow * STR + kk*32 + kg*8];
                #pragma unroll
                for (int nt = 0; nt < 8; nt++) {
                    bfrag wf = *(const bfrag*)&w2T[(nt*16 + l15) * 256 + nh*128 + kk*32 + kg*8];
                    acc2[nt].v = MFMA(hf, wf, acc2[nt].v);
                }
            }
        }

        // epilogue: residual in regs; rebuild h16A (own rows) for next layer
        #pragma unroll
        for (int nt = 0; nt < 8; nt++) {
            float b2v = fb2[nt*16 + l15];
            #pragma unroll
            for (int r = 0; r < 4; r++) hreg[nt][r] += acc2[nt].f[r] + b2v;
        }
        if (l < LLY - 1) {
            #pragma unroll
            for (int nt = 0; nt < 8; nt++) {
                int col = nt*16 + l15;
                #pragma unroll
                for (int r = 0; r < 4; r++)
                    Abuf[(wrow + kg*4 + r) * STR + col] = f2bf_bits(hreg[nt][r]);
            }
        }
    }

    // ---------- final LN + node-sum (proj commutes with mean) ----------
    const float* ng = pf + 4352;
    const float* nb = pf + 4480;
    float pacc[8];
    #pragma unroll
    for (int nt = 0; nt < 8; nt++) pacc[nt] = 0.f;
    #pragma unroll
    for (int r = 0; r < 4; r++) {
        float s1 = 0.f, sq = 0.f;
        #pragma unroll
        for (int nt = 0; nt < 8; nt++) { float x = hreg[nt][r]; s1 += x; sq = fmaf(x, x, sq); }
        #pragma unroll
        for (int m = 1; m <= 8; m <<= 1) { s1 += __shfl_xor(s1, m, 64); sq += __shfl_xor(sq, m, 64); }
        float mu = s1 * (1.f / 128.f);
        float var = sq * (1.f / 128.f) - mu * mu;
        float rs = rsqrtf(fmaxf(var, 0.f) + 1e-5f);
        #pragma unroll
        for (int nt = 0; nt < 8; nt++) {
            int col = nt*16 + l15;
            pacc[nt] += fmaf((hreg[nt][r] - mu) * rs, ng[col], nb[col]);
        }
    }
    #pragma unroll
    for (int nt = 0; nt < 8; nt++) {           // sum across kg groups (rows of this wave)
        pacc[nt] += __shfl_xor(pacc[nt], 16, 64);
        pacc[nt] += __shfl_xor(pacc[nt], 32, 64);
    }
    __syncthreads();                           // st2 free (last t2/s2 reads were pre-barrier2)
    if (kg == 0) {
        #pragma unroll
        for (int nt = 0; nt < 8; nt++) st2[wv * 128 + nt*16 + l15] = pacc[nt];
    }
    __syncthreads();
    // pooled mean -> st2[1024..1152)
    if (tid < 128) {
        float tot = 0.f;
        #pragma unroll
        for (int w = 0; w < 8; w++) tot += st2[w * 128 + tid];
        st2[1024 + tid] = tot * (1.f / 128.f);
    }
    __syncthreads();
    // proj: 4 k-quarters x 128 cols -> st2[1152..1664)
    {
        int e = tid & 127, kq = tid >> 7;
        float a = 0.f;
        #pragma unroll 4
        for (int k = kq * 32; k < kq * 32 + 32; k++)
            a = fmaf(st2[1024 + k], pf[4608 + k * 128 + e], a);
        st2[1152 + kq * 128 + e] = a;
    }
    __syncthreads();
    if (tid < 128)
        st2[1664 + tid] = st2[1152 + tid] + st2[1280 + tid] + st2[1408 + tid] + st2[1536 + tid]
                        + pf[20992 + tid];
    __syncthreads();
    if (tid < 64) {
        float a1 = pf[29312 + tid];
        #pragma unroll 4
        for (int k = 0; k < 128; k++) a1 = fmaf(st2[1664 + k], pf[21120 + k * 64 + tid], a1);
        st2[1792 + tid] = fmaxf(a1, 0.f);
    }
    __syncthreads();
    if (tid < OUTD) {
        float a2 = pf[33216 + tid];
        #pragma unroll 4
        for (int k = 0; k < 64; k++) a2 = fmaf(st2[1792 + k], pf[29376 + k * OUTD + tid], a2);
        if (isbf) ((bf16*)outv)[b * OUTD + tid] = __float2bfloat16(a2);
        else      ((float*)outv)[b * OUTD + tid] = a2;
    }
}

extern "C" void kernel_launch(void* const* d_in, const int* in_sizes, int n_in,
                              void* d_out, int out_size, void* d_ws, size_t ws_size,
                              hipStream_t stream)
{
    float* ws = (float*)d_ws;
    float* pf = ws;                                // compact f32 params [0..33276)
    int*   flag = (int*)(ws + 33280);
    u16* WT16   = (u16*)(ws + 33536);              // 65,536
    u16* w1T16  = WT16 + 65536;                    // 131,072
    u16* w2T16  = w1T16 + 131072;                  // 131,072
    u16* WAb16  = w2T16 + 131072;                  // 8,192
    u16* Aw16   = WAb16 + 8192;                    // 16,384
    u16* ew2p   = Aw16 + 16384;                    // 16,384

    SrcPtrs S;
    for (int i = 0; i < 28; i++) S.p[i] = d_in[i];

    hipFuncSetAttribute((const void*)k_net,
                        hipFuncAttributeMaxDynamicSharedMemorySize, LDSB);

    k_prep<<<1635, 256, 0, stream>>>(S, pf, WT16, w1T16, w2T16, WAb16, ew2p, Aw16, flag);
    k_net<<<BB, 512, LDSB, stream>>>(d_in[0], flag, pf,
                                     WT16, WAb16, Aw16, ew2p, w1T16, w2T16, d_out);
}